// Round 8
// baseline (306.068 us; speedup 1.0000x reference)
//
#include <hip/hip_runtime.h>
#include <hip/hip_bf16.h>

typedef unsigned short ushort_t;
typedef unsigned int   uint_t;
typedef unsigned long long ull_t;
typedef __attribute__((ext_vector_type(8))) short bf8;
typedef __attribute__((ext_vector_type(4))) float f32x4;

constexpr int N = 50000;
constexpr int E = 600000;
constexpr int D = 128;
constexpr int L = 2;
constexpr int NB = (N + 255) / 256;      // 196 scan blocks

constexpr int TR   = 48;                 // output rows per fused block
constexpr int NBLK = (N + TR - 1) / TR;  // 1042
constexpr int HSTR = 136;                // LDS row stride (u16)

__device__ __forceinline__ float us2f(ushort_t u) {
    union { uint_t i; float f; } c; c.i = (uint_t)u << 16; return c.f;
}
__device__ __forceinline__ ushort_t f2us(float f) {
    __hip_bfloat16 b = __float2bfloat16(f);
    return *(ushort_t*)&b;
}

// ---------------------------------------------------------------------------
// k_cast: tables fp32->bf16 packed, weights bf16 transposed, zero hist+state
// ---------------------------------------------------------------------------
__global__ __launch_bounds__(256) void k_cast(
    const float* __restrict__ ent, const float* __restrict__ rel,
    const float* __restrict__ tim, const float* __restrict__ Wi,
    const float* __restrict__ Wo, ushort_t* __restrict__ entb,
    ushort_t* __restrict__ relb, ushort_t* __restrict__ timb,
    ushort_t* __restrict__ WiT, ushort_t* __restrict__ WoT,
    int* __restrict__ hist, ull_t* __restrict__ state)
{
    size_t t = (size_t)blockIdx.x * 256 + threadIdx.x;
    if (t < 12500) ((int4*)hist)[t] = make_int4(0, 0, 0, 0);
    if (t < (size_t)NB) state[t] = 0ULL;
    if (t < 3276800) {
        const float2* s; uint_t* d; size_t off;
        if (t < 3200000)      { s = (const float2*)ent; d = (uint_t*)entb; off = t; }
        else if (t < 3212800) { s = (const float2*)rel; d = (uint_t*)relb; off = t - 3200000; }
        else                  { s = (const float2*)tim; d = (uint_t*)timb; off = t - 3212800; }
        float2 v = s[off];
        d[off] = (uint_t)f2us(v.x) | ((uint_t)f2us(v.y) << 16);
    } else {
        size_t u = t - 3276800;
        if (u < (size_t)L * 256 * 128) {
            int l = u / (256 * 128), r = u % (256 * 128);
            int n = r / 128, k = r % 128;
            WiT[u] = f2us(Wi[(size_t)l * 128 * 256 + k * 256 + n]);
        } else if (u < (size_t)L * 256 * 128 + L * 128 * 128) {
            size_t v = u - (size_t)L * 256 * 128;
            int l = v / (128 * 128), r = v % (128 * 128);
            int n = r / 128, k = r % 128;
            WoT[v] = f2us(Wo[(size_t)l * 128 * 128 + k * 128 + n]);
        }
    }
}

// ---------------------------------------------------------------------------
// k_hist: dst histogram + inverse permutation
// ---------------------------------------------------------------------------
__global__ __launch_bounds__(256) void k_hist(
    const int* __restrict__ dstp, int* __restrict__ hist,
    const int* __restrict__ perm, int* __restrict__ invp)
{
    int e = blockIdx.x * 256 + threadIdx.x;
    if (e < E) atomicAdd(&hist[dstp[e]], 1);
    if (e < N) invp[perm[e]] = e;
}

// ---------------------------------------------------------------------------
// k_scanp: single-pass exclusive scan (decoupled lookback, 196 blocks)
// state[b]: bits63-62 flag (1=aggregate, 2=inclusive), low 32 value
// ---------------------------------------------------------------------------
__global__ __launch_bounds__(256) void k_scanp(
    const int* __restrict__ hist, ull_t* __restrict__ state,
    int* __restrict__ cursor, int* __restrict__ rowst)
{
    int b = blockIdx.x;
    int tid = threadIdx.x;
    int i = b * 256 + tid;
    int v = (i < N) ? hist[i] : 0;
    int lane = tid & 63, wv = tid >> 6;
    int s = v;
    #pragma unroll
    for (int m = 1; m < 64; m <<= 1) {
        int t = __shfl_up(s, m, 64);
        if (lane >= m) s += t;
    }
    __shared__ int wsum[4];
    __shared__ int baseSh;
    if (lane == 63) wsum[wv] = s;
    __syncthreads();
    int off = 0;
    for (int w = 0; w < wv; w++) off += wsum[w];
    int total = wsum[0] + wsum[1] + wsum[2] + wsum[3];

    if (tid == 0) {
        atomicExch(&state[b], (1ULL << 62) | (uint_t)total);
        long long excl = 0;
        for (int p = b - 1; p >= 0; ) {
            ull_t st;
            do { st = atomicAdd(&state[p], 0ULL); } while ((st >> 62) == 0);
            excl += (uint_t)st;
            if ((st >> 62) == 2ULL) break;
            p--;
        }
        atomicExch(&state[b], (2ULL << 62) | (uint_t)(excl + total));
        baseSh = (int)excl;
    }
    __syncthreads();
    int ex = baseSh + off + s - v;
    if (i < N) { cursor[i] = ex; rowst[i] = ex; }
}

// packed record: x = src | (type<<16); y = time | (w_bf16<<16)
__global__ __launch_bounds__(256) void k_scatter(
    const int* __restrict__ eidx, const int* __restrict__ etype,
    const int* __restrict__ etime, const float* __restrict__ ew,
    int* __restrict__ cursor, int2* __restrict__ esort)
{
    int e = blockIdx.x * 256 + threadIdx.x;
    if (e >= E) return;
    int dst = eidx[E + e];
    int slot = atomicAdd(&cursor[dst], 1);
    int2 p;
    p.x = (eidx[e] & 0xffff) | (etype[e] << 16);
    p.y = (etime[e] & 0xffff) | ((int)f2us(ew[e]) << 16);
    esort[slot] = p;
}

// ---------------------------------------------------------------------------
// k_agg: one wave per dst row; unroll 8; fuses mean, L2-norm, perm gather
// ---------------------------------------------------------------------------
__global__ __launch_bounds__(256) void k_agg(
    const int2* __restrict__ esort, const int* __restrict__ rowst,
    const int* __restrict__ hist, const int* __restrict__ invp,
    const ushort_t* __restrict__ entb, const ushort_t* __restrict__ relb,
    const ushort_t* __restrict__ timb, ushort_t* __restrict__ xbf)
{
    int wv = threadIdx.x >> 6, lane = threadIdx.x & 63;
    int d = blockIdx.x * 4 + wv;
    if (d >= N) return;
    int beg = rowst[d];
    int n = hist[d];

    float s0[4] = {0.f, 0.f, 0.f, 0.f};
    float s1[4] = {0.f, 0.f, 0.f, 0.f};
    float sw[4] = {0.f, 0.f, 0.f, 0.f};

    int j = 0;
    for (; j + 7 < n; j += 8) {
        int2 rec[8];
        #pragma unroll
        for (int u = 0; u < 8; u++) rec[u] = esort[beg + j + u];
        #pragma unroll
        for (int u = 0; u < 8; u++) {
            int  sA = rec[u].x & 0xffff, tA = ((uint_t)rec[u].x) >> 16;
            int  mA = rec[u].y & 0xffff;
            float w = us2f((ushort_t)(((uint_t)rec[u].y) >> 16));
            uint_t va = *(const uint_t*)(entb + (size_t)sA * D + 2 * lane);
            uint_t vb = *(const uint_t*)(relb + (size_t)tA * D + 2 * lane);
            uint_t vc = *(const uint_t*)(timb + (size_t)mA * D + 2 * lane);
            int bk = u & 3;
            s0[bk] += (us2f(va & 0xffff) + us2f(vb & 0xffff) + us2f(vc & 0xffff)) * w;
            s1[bk] += (us2f(va >> 16)    + us2f(vb >> 16)    + us2f(vc >> 16))    * w;
            sw[bk] += w;
        }
    }
    for (; j + 3 < n; j += 4) {
        int2 rec[4];
        #pragma unroll
        for (int u = 0; u < 4; u++) rec[u] = esort[beg + j + u];
        #pragma unroll
        for (int u = 0; u < 4; u++) {
            int  sA = rec[u].x & 0xffff, tA = ((uint_t)rec[u].x) >> 16;
            int  mA = rec[u].y & 0xffff;
            float w = us2f((ushort_t)(((uint_t)rec[u].y) >> 16));
            uint_t va = *(const uint_t*)(entb + (size_t)sA * D + 2 * lane);
            uint_t vb = *(const uint_t*)(relb + (size_t)tA * D + 2 * lane);
            uint_t vc = *(const uint_t*)(timb + (size_t)mA * D + 2 * lane);
            s0[u] += (us2f(va & 0xffff) + us2f(vb & 0xffff) + us2f(vc & 0xffff)) * w;
            s1[u] += (us2f(va >> 16)    + us2f(vb >> 16)    + us2f(vc >> 16))    * w;
            sw[u] += w;
        }
    }
    for (; j < n; j++) {
        int2 p = esort[beg + j];
        int  sA = p.x & 0xffff, tA = ((uint_t)p.x) >> 16;
        int  mA = p.y & 0xffff;
        float w = us2f((ushort_t)(((uint_t)p.y) >> 16));
        uint_t va = *(const uint_t*)(entb + (size_t)sA * D + 2 * lane);
        uint_t vb = *(const uint_t*)(relb + (size_t)tA * D + 2 * lane);
        uint_t vc = *(const uint_t*)(timb + (size_t)mA * D + 2 * lane);
        s0[0] += (us2f(va & 0xffff) + us2f(vb & 0xffff) + us2f(vc & 0xffff)) * w;
        s1[0] += (us2f(va >> 16)    + us2f(vb >> 16)    + us2f(vc >> 16))    * w;
        sw[0] += w;
    }
    float a0 = (s0[0] + s0[1]) + (s0[2] + s0[3]);
    float a1 = (s1[0] + s1[1]) + (s1[2] + s1[3]);
    float wsum = (sw[0] + sw[1]) + (sw[2] + sw[3]);

    float inv = 1.0f / fmaxf(wsum, 1.0f);
    a0 *= inv; a1 *= inv;

    float ss = a0 * a0 + a1 * a1;
    #pragma unroll
    for (int m = 32; m >= 1; m >>= 1) ss += __shfl_xor(ss, m, 64);
    float sc = 1.0f / fmaxf(sqrtf(ss), 1e-12f);

    int orow = invp[d];
    uint_t out = (uint_t)f2us(a0 * sc) | ((uint_t)f2us(a1 * sc) << 16);
    *(uint_t*)(xbf + (size_t)orow * D + 2 * lane) = out;
}

// ---------------------------------------------------------------------------
// MFMA z/g tile + register affine scan (shared by both layers).
// Lane owns dims cz0=w*32+m and cz1=cz0+16.  Returns h per reg.
// ---------------------------------------------------------------------------
__device__ __forceinline__ void tile_scan(
    f32x4& az0, f32x4& az1, f32x4& ag0, f32x4& ag1,
    float bz0, float bz1, float bg0, float bg1,
    float Ad0, float Bd0, float Ad1, float Bd1,
    int rowStart, int quad, int m,
    float& carry0, float& carry1, float h0o[4], float h1o[4])
{
    float P0 = 1.f, Q0 = 0.f, P1 = 1.f, Q1 = 0.f;
    #pragma unroll
    for (int reg = 0; reg < 4; reg++) {
        int grr = rowStart + quad * 4 + reg;
        bool ok = (grr >= 0) && (grr < N);
        float z0 = az0[reg] + bz0, z1 = az1[reg] + bz1;
        float g0 = 1.f / (1.f + __expf(-(ag0[reg] + bg0)));
        float g1 = 1.f / (1.f + __expf(-(ag1[reg] + bg1)));
        float ca0 = ok ? g0 * Ad0 : 0.f, cb0 = ok ? Bd0 * z0 : 0.f;
        float ca1 = ok ? g1 * Ad1 : 0.f, cb1 = ok ? Bd1 * z1 : 0.f;
        az0[reg] = ca0; ag0[reg] = cb0;
        az1[reg] = ca1; ag1[reg] = cb1;
        P0 = ca0 * P0; Q0 = ca0 * Q0 + cb0;
        P1 = ca1 * P1; Q1 = ca1 * Q1 + cb1;
    }
    float Pp, Qp;
    Pp = __shfl_up(P0, 16, 64); Qp = __shfl_up(Q0, 16, 64);
    if (quad >= 1) { Q0 = P0 * Qp + Q0; P0 = P0 * Pp; }
    Pp = __shfl_up(P1, 16, 64); Qp = __shfl_up(Q1, 16, 64);
    if (quad >= 1) { Q1 = P1 * Qp + Q1; P1 = P1 * Pp; }
    Pp = __shfl_up(P0, 32, 64); Qp = __shfl_up(Q0, 32, 64);
    if (quad >= 2) { Q0 = P0 * Qp + Q0; P0 = P0 * Pp; }
    Pp = __shfl_up(P1, 32, 64); Qp = __shfl_up(Q1, 32, 64);
    if (quad >= 2) { Q1 = P1 * Qp + Q1; P1 = P1 * Pp; }
    float Pe0 = __shfl_up(P0, 16, 64), Qe0 = __shfl_up(Q0, 16, 64);
    float Pe1 = __shfl_up(P1, 16, 64), Qe1 = __shfl_up(Q1, 16, 64);
    if (quad == 0) { Pe0 = 1.f; Qe0 = 0.f; Pe1 = 1.f; Qe1 = 0.f; }
    float h0 = Pe0 * carry0 + Qe0;
    float h1 = Pe1 * carry1 + Qe1;
    float Pc0 = __shfl(P0, m + 48, 64), Qc0 = __shfl(Q0, m + 48, 64);
    float Pc1 = __shfl(P1, m + 48, 64), Qc1 = __shfl(Q1, m + 48, 64);
    carry0 = Pc0 * carry0 + Qc0;
    carry1 = Pc1 * carry1 + Qc1;
    #pragma unroll
    for (int reg = 0; reg < 4; reg++) {
        h0 = az0[reg] * h0 + ag0[reg];
        h1 = az1[reg] * h1 + ag1[reg];
        h0o[reg] = h0; h1o[reg] = h1;
    }
}

// ---------------------------------------------------------------------------
// k_fused: BOTH mamba layers in one kernel.  Block = 48 output rows.
// Layer-1 computed for rows [r0-32, r0+48); its LN output (x1) lives in LDS
// only.  Layer-2 consumes x1 with 16-row lookback.  ~37 KB LDS, 4 blocks/CU.
// ---------------------------------------------------------------------------
__global__ __launch_bounds__(256, 4) void k_fused(
    const ushort_t* __restrict__ xin, const ushort_t* __restrict__ WiT,
    const float* __restrict__ bi, const ushort_t* __restrict__ WoT,
    const float* __restrict__ bo, const float* __restrict__ Aw,
    const float* __restrict__ Bw, const float* __restrict__ lg,
    const float* __restrict__ lb, float* __restrict__ outf)
{
    __shared__ ushort_t hs[64 * HSTR];    // h (layer1: 64 rows; layer2: 48)
    __shared__ ushort_t x1s[64 * HSTR];   // layer-1 LN output, rows r0-16..r0+47
    __shared__ float redS[64 * 4], redQ[64 * 4], muA[64], rsA[64];

    int tid = threadIdx.x;
    int w = tid >> 6, lane = tid & 63;
    int quad = lane >> 4, m = lane & 15;
    int r0 = blockIdx.x * TR;

    const bf8 zero8 = {0, 0, 0, 0, 0, 0, 0, 0};
    const f32x4 zero4 = {0.f, 0.f, 0.f, 0.f};

    int cz0 = w * 32 + m, cz1 = cz0 + 16;

    // ================= LAYER 1 =================
    {
        int base1 = r0 - 32;
        float Ad0 = Aw[cz0], Bd0 = Bw[cz0], Ad1 = Aw[cz1], Bd1 = Bw[cz1];
        float bz0 = bi[cz0], bz1 = bi[cz1];
        float bg0 = bi[cz0 + 128], bg1 = bi[cz1 + 128];
        bf8 Bz0[4], Bz1[4], Bg0[4], Bg1[4];
        #pragma unroll
        for (int kb = 0; kb < 4; kb++) {
            int ko = kb * 32 + quad * 8;
            Bz0[kb] = *(const bf8*)(WiT + (size_t)cz0 * 128 + ko);
            Bz1[kb] = *(const bf8*)(WiT + (size_t)cz1 * 128 + ko);
            Bg0[kb] = *(const bf8*)(WiT + (size_t)(cz0 + 128) * 128 + ko);
            Bg1[kb] = *(const bf8*)(WiT + (size_t)(cz1 + 128) * 128 + ko);
        }
        float carry0 = 0.f, carry1 = 0.f;
        for (int rt = 0; rt < 5; rt++) {
            int gr = base1 + rt * 16 + m;
            bf8 a[4];
            if (gr >= 0 && gr < N) {
                #pragma unroll
                for (int kb = 0; kb < 4; kb++)
                    a[kb] = *(const bf8*)(xin + (size_t)gr * 128 + kb * 32 + quad * 8);
            } else {
                #pragma unroll
                for (int kb = 0; kb < 4; kb++) a[kb] = zero8;
            }
            f32x4 az0 = zero4, az1 = zero4, ag0 = zero4, ag1 = zero4;
            #pragma unroll
            for (int kb = 0; kb < 4; kb++) {
                az0 = __builtin_amdgcn_mfma_f32_16x16x32_bf16(a[kb], Bz0[kb], az0, 0, 0, 0);
                az1 = __builtin_amdgcn_mfma_f32_16x16x32_bf16(a[kb], Bz1[kb], az1, 0, 0, 0);
                ag0 = __builtin_amdgcn_mfma_f32_16x16x32_bf16(a[kb], Bg0[kb], ag0, 0, 0, 0);
                ag1 = __builtin_amdgcn_mfma_f32_16x16x32_bf16(a[kb], Bg1[kb], ag1, 0, 0, 0);
            }
            float h0[4], h1[4];
            tile_scan(az0, az1, ag0, ag1, bz0, bz1, bg0, bg1,
                      Ad0, Bd0, Ad1, Bd1, base1 + rt * 16, quad, m,
                      carry0, carry1, h0, h1);
            if (rt >= 1) {
                #pragma unroll
                for (int reg = 0; reg < 4; reg++) {
                    int lr = (rt - 1) * 16 + quad * 4 + reg;
                    hs[lr * HSTR + cz0] = f2us(h0[reg]);
                    hs[lr * HSTR + cz1] = f2us(h1[reg]);
                }
            }
        }
    }
    __syncthreads();

    // layer-1 out_proj + residual + LN over 64 rows (global r0-16 .. r0+47)
    {
        float bias0 = bo[cz0], bias1 = bo[cz1];
        bf8 b0[4], b1[4];
        #pragma unroll
        for (int kb = 0; kb < 4; kb++) {
            int ko = kb * 32 + quad * 8;
            b0[kb] = *(const bf8*)(WoT + (size_t)cz0 * 128 + ko);
            b1[kb] = *(const bf8*)(WoT + (size_t)cz1 * 128 + ko);
        }
        float y1[4][2][4];
        #pragma unroll
        for (int rt = 0; rt < 4; rt++) {
            bf8 a[4];
            #pragma unroll
            for (int kb = 0; kb < 4; kb++)
                a[kb] = *(const bf8*)(hs + (rt * 16 + m) * HSTR + kb * 32 + quad * 8);
            f32x4 acc0 = zero4, acc1 = zero4;
            #pragma unroll
            for (int kb = 0; kb < 4; kb++) {
                acc0 = __builtin_amdgcn_mfma_f32_16x16x32_bf16(a[kb], b0[kb], acc0, 0, 0, 0);
                acc1 = __builtin_amdgcn_mfma_f32_16x16x32_bf16(a[kb], b1[kb], acc1, 0, 0, 0);
            }
            #pragma unroll
            for (int reg = 0; reg < 4; reg++) {
                int gr = r0 - 16 + rt * 16 + quad * 4 + reg;
                float r0v = 0.f, r1v = 0.f;
                if (gr >= 0 && gr < N) {
                    r0v = us2f(xin[(size_t)gr * 128 + cz0]);
                    r1v = us2f(xin[(size_t)gr * 128 + cz1]);
                }
                y1[rt][0][reg] = acc0[reg] + bias0 + r0v;
                y1[rt][1][reg] = acc1[reg] + bias1 + r1v;
            }
        }
        // LN over 64 rows
        #pragma unroll
        for (int rt = 0; rt < 4; rt++)
            #pragma unroll
            for (int reg = 0; reg < 4; reg++) {
                float v0 = y1[rt][0][reg], v1 = y1[rt][1][reg];
                float s = v0 + v1, q = v0 * v0 + v1 * v1;
                #pragma unroll
                for (int mk = 1; mk <= 8; mk <<= 1) {
                    s += __shfl_xor(s, mk, 64);
                    q += __shfl_xor(q, mk, 64);
                }
                if (m == 0) {
                    int row = rt * 16 + quad * 4 + reg;
                    redS[row * 4 + w] = s;
                    redQ[row * 4 + w] = q;
                }
            }
        __syncthreads();
        if (tid < 64) {
            float s = redS[tid * 4] + redS[tid * 4 + 1] + redS[tid * 4 + 2] + redS[tid * 4 + 3];
            float q = redQ[tid * 4] + redQ[tid * 4 + 1] + redQ[tid * 4 + 2] + redQ[tid * 4 + 3];
            float mu = s * (1.f / 128.f);
            float var = q * (1.f / 128.f) - mu * mu;
            muA[tid] = mu;
            rsA[tid] = rsqrtf(var + 1e-5f);
        }
        __syncthreads();
        float gl0 = lg[cz0], gl1 = lg[cz1], bl0 = lb[cz0], bl1 = lb[cz1];
        #pragma unroll
        for (int rt = 0; rt < 4; rt++)
            #pragma unroll
            for (int reg = 0; reg < 4; reg++) {
                int row = rt * 16 + quad * 4 + reg;
                float mu = muA[row], rs = rsA[row];
                float v0 = (y1[rt][0][reg] - mu) * rs * gl0 + bl0;
                float v1 = (y1[rt][1][reg] - mu) * rs * gl1 + bl1;
                x1s[row * HSTR + cz0] = f2us(v0);
                x1s[row * HSTR + cz1] = f2us(v1);
            }
    }
    __syncthreads();

    // ================= LAYER 2 =================
    {
        const ushort_t* WiT2 = WiT + (size_t)256 * 128;
        const float* bi2 = bi + 256;
        float Ad0 = Aw[128 + cz0], Bd0 = Bw[128 + cz0];
        float Ad1 = Aw[128 + cz1], Bd1 = Bw[128 + cz1];
        float bz0 = bi2[cz0], bz1 = bi2[cz1];
        float bg0 = bi2[cz0 + 128], bg1 = bi2[cz1 + 128];
        bf8 Bz0[4], Bz1[4], Bg0[4], Bg1[4];
        #pragma unroll
        for (int kb = 0; kb < 4; kb++) {
            int ko = kb * 32 + quad * 8;
            Bz0[kb] = *(const bf8*)(WiT2 + (size_t)cz0 * 128 + ko);
            Bz1[kb] = *(const bf8*)(WiT2 + (size_t)cz1 * 128 + ko);
            Bg0[kb] = *(const bf8*)(WiT2 + (size_t)(cz0 + 128) * 128 + ko);
            Bg1[kb] = *(const bf8*)(WiT2 + (size_t)(cz1 + 128) * 128 + ko);
        }
        float carry0 = 0.f, carry1 = 0.f;
        float h2keep[4][2][4];   // h for local rows 16..63 stored via hs below
        (void)h2keep;
        for (int rt = 0; rt < 4; rt++) {
            bf8 a[4];
            #pragma unroll
            for (int kb = 0; kb < 4; kb++)
                a[kb] = *(const bf8*)(x1s + (rt * 16 + m) * HSTR + kb * 32 + quad * 8);
            f32x4 az0 = zero4, az1 = zero4, ag0 = zero4, ag1 = zero4;
            #pragma unroll
            for (int kb = 0; kb < 4; kb++) {
                az0 = __builtin_amdgcn_mfma_f32_16x16x32_bf16(a[kb], Bz0[kb], az0, 0, 0, 0);
                az1 = __builtin_amdgcn_mfma_f32_16x16x32_bf16(a[kb], Bz1[kb], az1, 0, 0, 0);
                ag0 = __builtin_amdgcn_mfma_f32_16x16x32_bf16(a[kb], Bg0[kb], ag0, 0, 0, 0);
                ag1 = __builtin_amdgcn_mfma_f32_16x16x32_bf16(a[kb], Bg1[kb], ag1, 0, 0, 0);
            }
            float h0[4], h1[4];
            tile_scan(az0, az1, ag0, ag1, bz0, bz1, bg0, bg1,
                      Ad0, Bd0, Ad1, Bd1, r0 - 16 + rt * 16, quad, m,
                      carry0, carry1, h0, h1);
            if (rt >= 1) {
                #pragma unroll
                for (int reg = 0; reg < 4; reg++) {
                    int lr = (rt - 1) * 16 + quad * 4 + reg;
                    hs[lr * HSTR + cz0] = f2us(h0[reg]);
                    hs[lr * HSTR + cz1] = f2us(h1[reg]);
                }
            }
        }
    }
    __syncthreads();

    // layer-2 out_proj + residual + LN over 48 rows -> fp32 out
    {
        const ushort_t* WoT2 = WoT + (size_t)128 * 128;
        const float* bo2 = bo + 128;
        float bias0 = bo2[cz0], bias1 = bo2[cz1];
        bf8 b0[4], b1[4];
        #pragma unroll
        for (int kb = 0; kb < 4; kb++) {
            int ko = kb * 32 + quad * 8;
            b0[kb] = *(const bf8*)(WoT2 + (size_t)cz0 * 128 + ko);
            b1[kb] = *(const bf8*)(WoT2 + (size_t)cz1 * 128 + ko);
        }
        float y2[3][2][4];
        #pragma unroll
        for (int rt = 0; rt < 3; rt++) {
            bf8 a[4];
            #pragma unroll
            for (int kb = 0; kb < 4; kb++)
                a[kb] = *(const bf8*)(hs + (rt * 16 + m) * HSTR + kb * 32 + quad * 8);
            f32x4 acc0 = zero4, acc1 = zero4;
            #pragma unroll
            for (int kb = 0; kb < 4; kb++) {
                acc0 = __builtin_amdgcn_mfma_f32_16x16x32_bf16(a[kb], b0[kb], acc0, 0, 0, 0);
                acc1 = __builtin_amdgcn_mfma_f32_16x16x32_bf16(a[kb], b1[kb], acc1, 0, 0, 0);
            }
            #pragma unroll
            for (int reg = 0; reg < 4; reg++) {
                int lrow = 16 + rt * 16 + quad * 4 + reg;   // x1s local row
                float r0v = us2f(x1s[lrow * HSTR + cz0]);
                float r1v = us2f(x1s[lrow * HSTR + cz1]);
                y2[rt][0][reg] = acc0[reg] + bias0 + r0v;
                y2[rt][1][reg] = acc1[reg] + bias1 + r1v;
            }
        }
        #pragma unroll
        for (int rt = 0; rt < 3; rt++)
            #pragma unroll
            for (int reg = 0; reg < 4; reg++) {
                float v0 = y2[rt][0][reg], v1 = y2[rt][1][reg];
                float s = v0 + v1, q = v0 * v0 + v1 * v1;
                #pragma unroll
                for (int mk = 1; mk <= 8; mk <<= 1) {
                    s += __shfl_xor(s, mk, 64);
                    q += __shfl_xor(q, mk, 64);
                }
                if (m == 0) {
                    int row = rt * 16 + quad * 4 + reg;
                    redS[row * 4 + w] = s;
                    redQ[row * 4 + w] = q;
                }
            }
        __syncthreads();
        if (tid < TR) {
            float s = redS[tid * 4] + redS[tid * 4 + 1] + redS[tid * 4 + 2] + redS[tid * 4 + 3];
            float q = redQ[tid * 4] + redQ[tid * 4 + 1] + redQ[tid * 4 + 2] + redQ[tid * 4 + 3];
            float mu = s * (1.f / 128.f);
            float var = q * (1.f / 128.f) - mu * mu;
            muA[tid] = mu;
            rsA[tid] = rsqrtf(var + 1e-5f);
        }
        __syncthreads();
        float gl0 = lg[128 + cz0], gl1 = lg[128 + cz1];
        float bl0 = lb[128 + cz0], bl1 = lb[128 + cz1];
        #pragma unroll
        for (int rt = 0; rt < 3; rt++)
            #pragma unroll
            for (int reg = 0; reg < 4; reg++) {
                int rr = rt * 16 + quad * 4 + reg;
                int gr = r0 + rr;
                if (gr < N) {
                    float mu = muA[rr], rs = rsA[rr];
                    outf[(size_t)gr * 128 + cz0] = (y2[rt][0][reg] - mu) * rs * gl0 + bl0;
                    outf[(size_t)gr * 128 + cz1] = (y2[rt][1][reg] - mu) * rs * gl1 + bl1;
                }
            }
    }
}

extern "C" void kernel_launch(void* const* d_in, const int* in_sizes, int n_in,
                              void* d_out, int out_size, void* d_ws, size_t ws_size,
                              hipStream_t stream)
{
    const int*   eidx  = (const int*)d_in[0];
    const int*   etype = (const int*)d_in[1];
    const int*   etime = (const int*)d_in[2];
    const float* ew    = (const float*)d_in[3];
    const int*   perm  = (const int*)d_in[4];
    const float* ent   = (const float*)d_in[5];
    const float* rel   = (const float*)d_in[6];
    const float* tim   = (const float*)d_in[7];
    const float* Wi    = (const float*)d_in[8];
    const float* bi    = (const float*)d_in[9];
    const float* Wo    = (const float*)d_in[10];
    const float* bo    = (const float*)d_in[11];
    const float* Aw    = (const float*)d_in[12];
    const float* Bw    = (const float*)d_in[13];
    const float* lg    = (const float*)d_in[14];
    const float* lbp   = (const float*)d_in[15];

    char* base = (char*)d_ws;
    size_t o = 0;
    ushort_t* xbf  = (ushort_t*)(base + o); o += (size_t)N * D * 2;
    ushort_t* entb = (ushort_t*)(base + o); o += (size_t)N * D * 2;
    ushort_t* relb = (ushort_t*)(base + o); o += (size_t)200 * D * 2;
    ushort_t* timb = (ushort_t*)(base + o); o += (size_t)1000 * D * 2;
    ushort_t* WiT  = (ushort_t*)(base + o); o += (size_t)L * 256 * 128 * 2;
    ushort_t* WoT  = (ushort_t*)(base + o); o += (size_t)L * 128 * 128 * 2;
    int2*     esort  = (int2*)(base + o);   o += (size_t)E * 8;
    ull_t*    state  = (ull_t*)(base + o);  o += (size_t)NB * 8 + 8;
    int*      hist   = (int*)(base + o);    o += (size_t)N * 4;
    int*      cursor = (int*)(base + o);    o += (size_t)N * 4;
    int*      rowst  = (int*)(base + o);    o += (size_t)N * 4;
    int*      invp   = (int*)(base + o);    o += (size_t)N * 4;

    k_cast   <<<13185, 256, 0, stream>>>(ent, rel, tim, Wi, Wo,
                                         entb, relb, timb, WiT, WoT, hist, state);
    k_hist   <<<(E + 255) / 256, 256, 0, stream>>>(eidx + E, hist, perm, invp);
    k_scanp  <<<NB, 256, 0, stream>>>(hist, state, cursor, rowst);
    k_scatter<<<(E + 255) / 256, 256, 0, stream>>>(eidx, etype, etime, ew,
                                                   cursor, esort);
    k_agg    <<<(N + 3) / 4, 256, 0, stream>>>(esort, rowst, hist, invp,
                                               entb, relb, timb, xbf);
    k_fused  <<<NBLK, 256, 0, stream>>>(xbf, WiT, bi, WoT, bo, Aw, Bw,
                                        lg, lbp, (float*)d_out);
}